// Round 13
// baseline (222.279 us; speedup 1.0000x reference)
//
#include <hip/hip_runtime.h>
#include <math.h>

#define LATENT   1024
#define WORD     64
#define NB_WORD  8192
#define BATCH    2048
#define NROWS    (BATCH * LATENT / WORD)   // 32768
#define NELEM    (BATCH * LATENT)          // 2097152

#define NCHUNK   8
#define CWCHUNK  (NB_WORD / NCHUNK)        // 1024
#define TPC      (CWCHUNK / 16)            // 64 tiles per chunk
#define NTILE    (NB_WORD / 16)            // 512 tiles
#define PKTS     (NTILE * 6 * 64)          // 196608 16B packets

typedef __attribute__((ext_vector_type(8))) __bf16 bf16x8;
typedef __attribute__((ext_vector_type(4))) float  f32x4;

// ------- kernel 1: fused e2 + epack (one emb read, r1 e2 chain order) -
__global__ __launch_bounds__(256) void vq_prep_kernel(
    const float* __restrict__ emb, float* __restrict__ e2,
    bf16x8* __restrict__ epack) {
    int m = blockIdx.x * 256 + threadIdx.x;
    int tile = m >> 4, l15 = m & 15;
    float s0 = 0.f, s1 = 0.f, s2 = 0.f, s3 = 0.f;
#pragma unroll
    for (int Ks = 0; Ks < 2; ++Ks) {
#pragma unroll
        for (int q = 0; q < 4; ++q) {
            const float4* s4 = reinterpret_cast<const float4*>(
                emb + (size_t)m * WORD + Ks * 32 + q * 8);
            float4 a = s4[0], b = s4[1];
            float tv[8] = {a.x, a.y, a.z, a.w, b.x, b.y, b.z, b.w};
            bf16x8 oh, om, ol;
#pragma unroll
            for (int e = 0; e < 8; ++e) {
                float v = tv[e];
                if ((e & 3) == 0) s0 = fmaf(v, v, s0);
                else if ((e & 3) == 1) s1 = fmaf(v, v, s1);
                else if ((e & 3) == 2) s2 = fmaf(v, v, s2);
                else s3 = fmaf(v, v, s3);
                __bf16 h  = (__bf16)v;
                float r1  = v - (float)h;
                __bf16 mm = (__bf16)r1;
                float r2  = r1 - (float)mm;
                __bf16 lo = (__bf16)r2;
                oh[e] = h; om[e] = mm; ol[e] = lo;
            }
            size_t base = ((size_t)tile * 6) * 64 + q * 16 + l15;
            epack[base + (size_t)(0 * 2 + Ks) * 64] = oh;
            epack[base + (size_t)(1 * 2 + Ks) * 64] = om;
            epack[base + (size_t)(2 * 2 + Ks) * 64] = ol;
        }
    }
    e2[m] = (s0 + s1) + (s2 + s3);
}

__device__ __forceinline__ void gload_lds16(const char* g, char* l) {
    __builtin_amdgcn_global_load_lds(
        (const __attribute__((address_space(1))) void*)g,
        (__attribute__((address_space(3))) void*)l, 16, 0, 0);
}

#define MFMA16 __builtin_amdgcn_mfma_f32_16x16x32_bf16

// ---------------- kernel 2: MFMA split-bf16 argmin --------------------
// Barrier-free; wave-private LDS double-buffer + counted vmcnt pipeline.
// 4 independent waves/block; wave = 32 rows x 1024-cw chunk (64 tiles).
// Per phase: issue 6 gload_lds + 1 e2 load for tile t+1 (un-sinkable, in
// flight across this phase) -> s_waitcnt vmcnt(7) (tile t ready) -> 6
// ds_read_b128 -> 24 MFMA round-robined over 4 acc chains -> fold.
__global__ __launch_bounds__(256)
__attribute__((amdgpu_waves_per_eu(4, 4)))
void vq_argmin_kernel(
    const float* __restrict__ z, const bf16x8* __restrict__ epack,
    const float* __restrict__ e2, unsigned long long* __restrict__ best) {

    __shared__ __align__(16) char le[4][2][6144];   // per-wave dbuf, 48 KB

    const int tid   = threadIdx.x;
    const int lane  = tid & 63;
    const int wband = tid >> 6;               // 0..3
    const int l15   = lane & 15;
    const int l4    = lane >> 4;              // 0..3
    const int rowbase   = blockIdx.x * 128 + wband * 32;
    const int tile0     = blockIdx.y * TPC;
    const int chunkbase = blockIdx.y * CWCHUNK;
    const float* e2g    = e2 + chunkbase;
    const int off       = (blockIdx.x & 15) * 4;   // tile start offset (L2 spread)

    // ---- build A-frags (z 3-way bf16 split) in registers ----
    bf16x8 A[2][2][3];                         // [mt][Ks][spl]
    const float4* zf4 = reinterpret_cast<const float4*>(z);
#pragma unroll
    for (int mt = 0; mt < 2; ++mt) {
        int row = rowbase + mt * 16 + l15;
#pragma unroll
        for (int Ks = 0; Ks < 2; ++Ks) {
            float4 v0 = zf4[(size_t)row * 16 + Ks * 8 + l4 * 2];
            float4 v1 = zf4[(size_t)row * 16 + Ks * 8 + l4 * 2 + 1];
            float tv[8] = {v0.x, v0.y, v0.z, v0.w, v1.x, v1.y, v1.z, v1.w};
#pragma unroll
            for (int e = 0; e < 8; ++e) {
                float v = tv[e];
                __bf16 h  = (__bf16)v;
                float r1  = v - (float)h;
                __bf16 m  = (__bf16)r1;
                float r2  = r1 - (float)m;
                __bf16 lo = (__bf16)r2;
                A[mt][Ks][0][e] = h;
                A[mt][Ks][1][e] = m;
                A[mt][Ks][2][e] = lo;
            }
        }
    }

    char* lbase = &le[wband][0][0];

    // ---- prologue: issue tile 'off' batch into buf0 + its e2 ----
    {
        const char* src = (const char*)epack + (size_t)(tile0 + off) * 6144 + lane * 16;
#pragma unroll
        for (int j = 0; j < 6; ++j)
            gload_lds16(src + j * 1024, lbase + j * 1024);
    }
    float e2A = e2g[off * 16 + l15];
    float e2B;

    float bestd[8] = {INFINITY, INFINITY, INFINITY, INFINITY,
                      INFINITY, INFINITY, INFINITY, INFINITY};
    int   bt[8]    = {0, 0, 0, 0, 0, 0, 0, 0};

// one phase: stage tile TNXT into the other buffer, wait for tile TCUR,
// compute+fold tile TCUR from buffer at byte offset BUFOFF.
#define PHASE(BUFOFF, E2CUR, E2NXT, TCUR, TNXT)                             \
    {                                                                       \
        const char* srcn = (const char*)epack +                             \
                           (size_t)(tile0 + (TNXT)) * 6144 + lane * 16;     \
        char* dstn = lbase + ((BUFOFF) ^ 6144);                             \
        _Pragma("unroll")                                                   \
        for (int j = 0; j < 6; ++j)                                         \
            gload_lds16(srcn + j * 1024, dstn + j * 1024);                  \
        E2NXT = e2g[(TNXT) * 16 + l15];                                     \
        asm volatile("s_waitcnt vmcnt(7)" ::: "memory");                    \
        asm volatile("" :: "v"(E2CUR));  /* pin: loaded last phase */       \
        const char* bb = lbase + (BUFOFF) + lane * 16;                      \
        bf16x8 Bh0 = *reinterpret_cast<const bf16x8*>(bb);                  \
        bf16x8 Bh1 = *reinterpret_cast<const bf16x8*>(bb + 1024);           \
        bf16x8 Bm0 = *reinterpret_cast<const bf16x8*>(bb + 2048);           \
        bf16x8 Bm1 = *reinterpret_cast<const bf16x8*>(bb + 3072);           \
        bf16x8 Bl0 = *reinterpret_cast<const bf16x8*>(bb + 4096);           \
        bf16x8 Bl1 = *reinterpret_cast<const bf16x8*>(bb + 5120);           \
        f32x4 a00 = {0.f, 0.f, 0.f, 0.f};                                   \
        f32x4 a01 = {0.f, 0.f, 0.f, 0.f};                                   \
        f32x4 a10 = {0.f, 0.f, 0.f, 0.f};                                   \
        f32x4 a11 = {0.f, 0.f, 0.f, 0.f};                                   \
        /* 6 rounds x 4 chains; per-chain order: hh, mh, lh, mm, hm, hl */  \
        a00 = MFMA16(A[0][0][0], Bh0, a00, 0, 0, 0);                        \
        a10 = MFMA16(A[1][0][0], Bh0, a10, 0, 0, 0);                        \
        a01 = MFMA16(A[0][1][0], Bh1, a01, 0, 0, 0);                        \
        a11 = MFMA16(A[1][1][0], Bh1, a11, 0, 0, 0);                        \
        a00 = MFMA16(A[0][0][1], Bh0, a00, 0, 0, 0);                        \
        a10 = MFMA16(A[1][0][1], Bh0, a10, 0, 0, 0);                        \
        a01 = MFMA16(A[0][1][1], Bh1, a01, 0, 0, 0);                        \
        a11 = MFMA16(A[1][1][1], Bh1, a11, 0, 0, 0);                        \
        a00 = MFMA16(A[0][0][2], Bh0, a00, 0, 0, 0);                        \
        a10 = MFMA16(A[1][0][2], Bh0, a10, 0, 0, 0);                        \
        a01 = MFMA16(A[0][1][2], Bh1, a01, 0, 0, 0);                        \
        a11 = MFMA16(A[1][1][2], Bh1, a11, 0, 0, 0);                        \
        a00 = MFMA16(A[0][0][1], Bm0, a00, 0, 0, 0);                        \
        a10 = MFMA16(A[1][0][1], Bm0, a10, 0, 0, 0);                        \
        a01 = MFMA16(A[0][1][1], Bm1, a01, 0, 0, 0);                        \
        a11 = MFMA16(A[1][1][1], Bm1, a11, 0, 0, 0);                        \
        a00 = MFMA16(A[0][0][0], Bm0, a00, 0, 0, 0);                        \
        a10 = MFMA16(A[1][0][0], Bm0, a10, 0, 0, 0);                        \
        a01 = MFMA16(A[0][1][0], Bm1, a01, 0, 0, 0);                        \
        a11 = MFMA16(A[1][1][0], Bm1, a11, 0, 0, 0);                        \
        a00 = MFMA16(A[0][0][0], Bl0, a00, 0, 0, 0);                        \
        a10 = MFMA16(A[1][0][0], Bl0, a10, 0, 0, 0);                        \
        a01 = MFMA16(A[0][1][0], Bl1, a01, 0, 0, 0);                        \
        a11 = MFMA16(A[1][1][0], Bl1, a11, 0, 0, 0);                        \
        _Pragma("unroll")                                                   \
        for (int v = 0; v < 4; ++v) {                                       \
            float d0 = fmaf(-2.0f, a00[v] + a01[v], E2CUR);                 \
            if (d0 < bestd[v])     { bestd[v]     = d0; bt[v]     = (TCUR); } \
            float d1 = fmaf(-2.0f, a10[v] + a11[v], E2CUR);                 \
            if (d1 < bestd[4 + v]) { bestd[4 + v] = d1; bt[4 + v] = (TCUR); } \
        }                                                                   \
    }

    int t0 = off;
    for (int tt = 0; tt < TPC; tt += 2) {
        int t1 = t0 + 1; if (t1 >= TPC) t1 -= TPC;
        int t2 = t1 + 1; if (t2 >= TPC) t2 -= TPC;   // wrap: harmless reload
        PHASE(0,    e2A, e2B, t0, t1);
        PHASE(6144, e2B, e2A, t1, t2);
        t0 = t2;
    }
#undef PHASE

    // ---- cross-lane min over the 16 cw-lanes, then atomicMin merge ----
    // (u64 pack: min dist, tie -> min cw == first occurrence; visit-order
    //  independent, so the tile-offset stagger is safe.)
#pragma unroll
    for (int mt = 0; mt < 2; ++mt) {
#pragma unroll
        for (int v = 0; v < 4; ++v) {
            float bd = bestd[mt * 4 + v];
            int   cw = chunkbase + bt[mt * 4 + v] * 16 + l15;
            unsigned db = __float_as_uint(bd);
            db = (db & 0x80000000u) ? ~db : (db | 0x80000000u);
            unsigned long long key =
                ((unsigned long long)db << 32) | (unsigned)cw;
#pragma unroll
            for (int off2 = 1; off2 < 16; off2 <<= 1) {
                unsigned long long o = __shfl_xor(key, off2);
                key = (o < key) ? o : key;
            }
            if (l15 == 0)
                atomicMin(&best[rowbase + mt * 16 + l4 * 4 + v], key);
        }
    }
}

// ---------------- kernel 3: gather + straight-through output + loss ---
__global__ __launch_bounds__(256) void vq_out_kernel(
    const float* __restrict__ z, const float* __restrict__ emb,
    const unsigned long long* __restrict__ best,
    float* __restrict__ out, float* __restrict__ lsum) {
    const int base = (blockIdx.x * 256 + threadIdx.x) * 8;
    const int row  = base >> 6;
    const int m    = (int)(best[row] & 0xFFFFFFFFull);

    const float4* zp = reinterpret_cast<const float4*>(z + base);
    const float4* qp = reinterpret_cast<const float4*>(emb + (size_t)m * WORD + (base & 63));
    float4* op = reinterpret_cast<float4*>(out + base);

    float s = 0.f;
#pragma unroll
    for (int i = 0; i < 2; ++i) {
        float4 zv = zp[i];
        float4 qv = qp[i];
        float dx = qv.x - zv.x, dy = qv.y - zv.y, dz = qv.z - zv.z, dw = qv.w - zv.w;
        float4 ov;
        ov.x = zv.x + dx; ov.y = zv.y + dy; ov.z = zv.z + dz; ov.w = zv.w + dw;
        op[i] = ov;
        s += dx*dx + dy*dy + dz*dz + dw*dw;
    }

#pragma unroll
    for (int off = 32; off > 0; off >>= 1) s += __shfl_down(s, off);
    __shared__ float wsum[4];
    int lane = threadIdx.x & 63, wid = threadIdx.x >> 6;
    if (lane == 0) wsum[wid] = s;
    __syncthreads();
    if (threadIdx.x == 0)
        atomicAdd(lsum, (wsum[0] + wsum[1]) + (wsum[2] + wsum[3]));
}

// ---------------- kernel 4: finalize loss -----------------------------
__global__ void vq_loss_kernel(const float* __restrict__ lsum,
                               float* __restrict__ loss_out) {
    float mean = lsum[0] * (1.0f / (float)NELEM);
    loss_out[0] = mean + 2.5f * mean;
}

extern "C" void kernel_launch(void* const* d_in, const int* in_sizes, int n_in,
                              void* d_out, int out_size, void* d_ws, size_t ws_size,
                              hipStream_t stream) {
    const float* z   = (const float*)d_in[0];   // z_mean (2048,1024)
    // d_in[1] = z_log_var, unused by the reference
    const float* emb = (const float*)d_in[2];   // (8192,64)
    float* out = (float*)d_out;                 // [z_q_st flat (2097152), loss]

    // ws layout: epack 3 MB | e2 32 KB | best 256 KB | lsum 4 B
    bf16x8* epack = (bf16x8*)d_ws;
    float*  e2    = (float*)((char*)d_ws + (size_t)PKTS * 16);
    unsigned long long* best =
        (unsigned long long*)((char*)e2 + NB_WORD * sizeof(float));
    float* lsum = (float*)((char*)best + NROWS * sizeof(unsigned long long));

    hipMemsetAsync(best, 0xFF, NROWS * sizeof(unsigned long long), stream);
    hipMemsetAsync(lsum, 0, sizeof(float), stream);

    vq_prep_kernel<<<NB_WORD / 256, 256, 0, stream>>>(emb, e2, epack);
    vq_argmin_kernel<<<dim3(NROWS / 128, NCHUNK), 256, 0, stream>>>(
        z, epack, e2, best);
    vq_out_kernel<<<NELEM / (256 * 8), 256, 0, stream>>>(z, emb, best, out, lsum);
    vq_loss_kernel<<<1, 1, 0, stream>>>(lsum, out + NELEM);
}

// Round 14
// 200.148 us; speedup vs baseline: 1.1106x; 1.1106x over previous
//
#include <hip/hip_runtime.h>
#include <math.h>

#define LATENT   1024
#define WORD     64
#define NB_WORD  8192
#define BATCH    2048
#define NROWS    (BATCH * LATENT / WORD)   // 32768
#define NELEM    (BATCH * LATENT)          // 2097152

#define NCHUNK   8
#define CWCHUNK  (NB_WORD / NCHUNK)        // 1024
#define TPC      (CWCHUNK / 16)            // 64 tiles per chunk
#define NTILE    (NB_WORD / 16)            // 512 tiles
#define PKTS     (NTILE * 6 * 64)          // 196608 16B packets

typedef __attribute__((ext_vector_type(8))) __bf16 bf16x8;
typedef __attribute__((ext_vector_type(4))) float  f32x4;

// ------- kernel 1: fused e2 + epack (one emb read, r1 e2 chain order) -
__global__ __launch_bounds__(256) void vq_prep_kernel(
    const float* __restrict__ emb, float* __restrict__ e2,
    bf16x8* __restrict__ epack) {
    int m = blockIdx.x * 256 + threadIdx.x;
    int tile = m >> 4, l15 = m & 15;
    float s0 = 0.f, s1 = 0.f, s2 = 0.f, s3 = 0.f;
#pragma unroll
    for (int Ks = 0; Ks < 2; ++Ks) {
#pragma unroll
        for (int q = 0; q < 4; ++q) {
            const float4* s4 = reinterpret_cast<const float4*>(
                emb + (size_t)m * WORD + Ks * 32 + q * 8);
            float4 a = s4[0], b = s4[1];
            float tv[8] = {a.x, a.y, a.z, a.w, b.x, b.y, b.z, b.w};
            bf16x8 oh, om, ol;
#pragma unroll
            for (int e = 0; e < 8; ++e) {
                float v = tv[e];
                if ((e & 3) == 0) s0 = fmaf(v, v, s0);
                else if ((e & 3) == 1) s1 = fmaf(v, v, s1);
                else if ((e & 3) == 2) s2 = fmaf(v, v, s2);
                else s3 = fmaf(v, v, s3);
                __bf16 h  = (__bf16)v;
                float r1  = v - (float)h;
                __bf16 mm = (__bf16)r1;
                float r2  = r1 - (float)mm;
                __bf16 lo = (__bf16)r2;
                oh[e] = h; om[e] = mm; ol[e] = lo;
            }
            size_t base = ((size_t)tile * 6) * 64 + q * 16 + l15;
            epack[base + (size_t)(0 * 2 + Ks) * 64] = oh;
            epack[base + (size_t)(1 * 2 + Ks) * 64] = om;
            epack[base + (size_t)(2 * 2 + Ks) * 64] = ol;
        }
    }
    e2[m] = (s0 + s1) + (s2 + s3);
}

__device__ __forceinline__ void gload_lds16(const char* g, char* l) {
    __builtin_amdgcn_global_load_lds(
        (const __attribute__((address_space(1))) void*)g,
        (__attribute__((address_space(3))) void*)l, 16, 0, 0);
}

#define MFMA16 __builtin_amdgcn_mfma_f32_16x16x32_bf16
#define SBAR() __builtin_amdgcn_sched_barrier(0)

// ---------------- kernel 2: MFMA split-bf16 argmin --------------------
// r10 base (shared staging, raw barrier, stagger) + r14: 4 acc chains,
// delayed fold SLICED INTO the MFMA cluster with sched_barrier(0) pins,
// so fold VALU issues in the matrix pipe's shadow instead of after it.
__global__ __launch_bounds__(256)
__attribute__((amdgpu_waves_per_eu(3, 3)))
void vq_argmin_kernel(
    const float* __restrict__ z, const bf16x8* __restrict__ epack,
    const float* __restrict__ e2, unsigned long long* __restrict__ best) {

    // phase stagger: rounds are equal-length, so initial offsets persist
    {
        int ph = blockIdx.x & 3;
        if (ph == 1) __builtin_amdgcn_s_sleep(2);
        else if (ph == 2) __builtin_amdgcn_s_sleep(4);
        else if (ph == 3) __builtin_amdgcn_s_sleep(6);
    }

    __shared__ __align__(16) char le[2 * 6144];

    const int tid   = threadIdx.x;
    const int lane  = tid & 63;
    const int wband = tid >> 6;               // 0..3
    const int l15   = lane & 15;
    const int l4    = lane >> 4;              // 0..3
    const int rowbase   = blockIdx.x * 128 + wband * 32;
    const int tile0     = blockIdx.y * TPC;
    const int chunkbase = blockIdx.y * CWCHUNK;
    const float* e2g    = e2 + chunkbase;
    const int off       = (blockIdx.x & 15) * 4;   // tile start offset (L2 spread)

    // ---- build A-frags (z 3-way bf16 split) in registers ----
    bf16x8 A[2][2][3];                         // [mt][Ks][spl]
    const float4* zf4 = reinterpret_cast<const float4*>(z);
#pragma unroll
    for (int mt = 0; mt < 2; ++mt) {
        int row = rowbase + mt * 16 + l15;
#pragma unroll
        for (int Ks = 0; Ks < 2; ++Ks) {
            float4 v0 = zf4[(size_t)row * 16 + Ks * 8 + l4 * 2];
            float4 v1 = zf4[(size_t)row * 16 + Ks * 8 + l4 * 2 + 1];
            float tv[8] = {v0.x, v0.y, v0.z, v0.w, v1.x, v1.y, v1.z, v1.w};
#pragma unroll
            for (int e = 0; e < 8; ++e) {
                float v = tv[e];
                __bf16 h  = (__bf16)v;
                float r1  = v - (float)h;
                __bf16 m  = (__bf16)r1;
                float r2  = r1 - (float)m;
                __bf16 lo = (__bf16)r2;
                A[mt][Ks][0][e] = h;
                A[mt][Ks][1][e] = m;
                A[mt][Ks][2][e] = lo;
            }
        }
    }

    // ---- prologue: issue DMA for tile 'off' into buf 0 ----
    {
        const char* src = (const char*)epack + (size_t)(tile0 + off) * 6144;
        gload_lds16(src + wband * 1024 + lane * 16, le + wband * 1024);
        if (wband < 2)
            gload_lds16(src + (4 + wband) * 1024 + lane * 16,
                        le + (4 + wband) * 1024);
    }

    float bestd[8] = {INFINITY, INFINITY, INFINITY, INFINITY,
                      INFINITY, INFINITY, INFINITY, INFINITY};
    int   bt[8]    = {0, 0, 0, 0, 0, 0, 0, 0};

    // two named accumulator-chain sets (x computed while y folds, then swap)
    f32x4 x00, x01, x10, x11;
    f32x4 y00 = {0.f,0.f,0.f,0.f}, y01 = {0.f,0.f,0.f,0.f};
    f32x4 y10 = {0.f,0.f,0.f,0.f}, y11 = {0.f,0.f,0.f,0.f};
    float e2x, e2y = INFINITY;     // INF: first fold is a no-op (INF<INF false)

// one fold slice (element V) of chain set P** at e2 E2P, tile TP
#define FOLD1(P00,P01,P10,P11, E2P, TP, V)                                  \
    do {                                                                    \
        float d0_ = fmaf(-2.0f, P00[V] + P01[V], E2P);                      \
        if (d0_ < bestd[V])     { bestd[V]     = d0_; bt[V]     = (TP); }   \
        float d1_ = fmaf(-2.0f, P10[V] + P11[V], E2P);                      \
        if (d1_ < bestd[4+(V)]) { bestd[4+(V)] = d1_; bt[4+(V)] = (TP); }   \
    } while (0)

// 4 independent MFMAs, one per chain
#define GROUP(SPL, B0, B1, C00,C01,C10,C11)                                 \
    C00 = MFMA16(A[0][0][SPL], B0, C00, 0, 0, 0);                           \
    C10 = MFMA16(A[1][0][SPL], B0, C10, 0, 0, 0);                           \
    C01 = MFMA16(A[0][1][SPL], B1, C01, 0, 0, 0);                           \
    C11 = MFMA16(A[1][1][SPL], B1, C11, 0, 0, 0);

// phase: compute tile TCUR (buf BUFOFF) into C**, fold P** (tile TP),
// stage tile TNXT into the other buffer, load e2 of TCUR into E2C.
#define PHASE(BUFOFF, C00,C01,C10,C11, P00,P01,P10,P11, E2C, E2P, TCUR, TNXT, TP) \
    {                                                                       \
        asm volatile("s_waitcnt vmcnt(0)" ::: "memory");                    \
        SBAR();                                                             \
        __builtin_amdgcn_s_barrier();      /* buf BUFOFF fully staged */    \
        const char* bb = le + (BUFOFF) + lane * 16;                         \
        bf16x8 Bh0 = *reinterpret_cast<const bf16x8*>(bb);                  \
        bf16x8 Bh1 = *reinterpret_cast<const bf16x8*>(bb + 1024);           \
        bf16x8 Bm0 = *reinterpret_cast<const bf16x8*>(bb + 2048);           \
        bf16x8 Bm1 = *reinterpret_cast<const bf16x8*>(bb + 3072);           \
        bf16x8 Bl0 = *reinterpret_cast<const bf16x8*>(bb + 4096);           \
        bf16x8 Bl1 = *reinterpret_cast<const bf16x8*>(bb + 5120);           \
        const char* srcn = (const char*)epack +                             \
                           (size_t)(tile0 + (TNXT)) * 6144;                 \
        char* dstn = le + ((BUFOFF) ^ 6144);                                \
        gload_lds16(srcn + wband * 1024 + lane * 16, dstn + wband * 1024);  \
        if (wband < 2)                                                      \
            gload_lds16(srcn + (4 + wband) * 1024 + lane * 16,              \
                        dstn + (4 + wband) * 1024);                         \
        E2C = e2g[(TCUR) * 16 + l15];                                       \
        __builtin_amdgcn_s_setprio(1);                                      \
        SBAR();                                                             \
        /* fold slices v0,v1 + acc inits fill the ds_read latency */        \
        FOLD1(P00,P01,P10,P11, E2P, TP, 0);                                 \
        FOLD1(P00,P01,P10,P11, E2P, TP, 1);                                 \
        C00 = (f32x4){0.f,0.f,0.f,0.f};                                     \
        C01 = (f32x4){0.f,0.f,0.f,0.f};                                     \
        C10 = (f32x4){0.f,0.f,0.f,0.f};                                     \
        C11 = (f32x4){0.f,0.f,0.f,0.f};                                     \
        SBAR();                                                             \
        GROUP(0, Bh0, Bh1, C00,C01,C10,C11)   /* hh */                      \
        SBAR();                                                             \
        FOLD1(P00,P01,P10,P11, E2P, TP, 2);                                 \
        SBAR();                                                             \
        GROUP(1, Bh0, Bh1, C00,C01,C10,C11)   /* mh */                      \
        SBAR();                                                             \
        FOLD1(P00,P01,P10,P11, E2P, TP, 3);                                 \
        SBAR();                                                             \
        GROUP(2, Bh0, Bh1, C00,C01,C10,C11)   /* lh */                      \
        GROUP(1, Bm0, Bm1, C00,C01,C10,C11)   /* mm */                      \
        GROUP(0, Bm0, Bm1, C00,C01,C10,C11)   /* hm */                      \
        GROUP(0, Bl0, Bl1, C00,C01,C10,C11)   /* hl */                      \
        __builtin_amdgcn_s_setprio(0);                                      \
    }

    int t0 = off;
    int tp = 0;                     // tile of pending y-fold (dummy at entry)
    for (int tt = 0; tt < TPC; tt += 2) {
        int t1 = t0 + 1; if (t1 >= TPC) t1 -= TPC;
        int t2 = t1 + 1; if (t2 >= TPC) t2 -= TPC;   // wrap: harmless reload
        PHASE(0,    x00,x01,x10,x11, y00,y01,y10,y11, e2x, e2y, t0, t1, tp);
        PHASE(6144, y00,y01,y10,y11, x00,x01,x10,x11, e2y, e2x, t1, t2, t0);
        tp = t1;
        t0 = t2;
    }
#undef PHASE

    // ---- epilogue: fold the last phase (y set) ----
    asm volatile("s_waitcnt vmcnt(0)" ::: "memory");
    FOLD1(y00,y01,y10,y11, e2y, tp, 0);
    FOLD1(y00,y01,y10,y11, e2y, tp, 1);
    FOLD1(y00,y01,y10,y11, e2y, tp, 2);
    FOLD1(y00,y01,y10,y11, e2y, tp, 3);
#undef FOLD1
#undef GROUP

    // ---- cross-lane min over the 16 cw-lanes, then atomicMin merge ----
    // (u64 pack: min dist, tie -> min cw == first occurrence; visit-order
    //  independent, so the tile-offset stagger is safe.)
#pragma unroll
    for (int mt = 0; mt < 2; ++mt) {
#pragma unroll
        for (int v = 0; v < 4; ++v) {
            float bd = bestd[mt * 4 + v];
            int   cw = chunkbase + bt[mt * 4 + v] * 16 + l15;
            unsigned db = __float_as_uint(bd);
            db = (db & 0x80000000u) ? ~db : (db | 0x80000000u);
            unsigned long long key =
                ((unsigned long long)db << 32) | (unsigned)cw;
#pragma unroll
            for (int off2 = 1; off2 < 16; off2 <<= 1) {
                unsigned long long o = __shfl_xor(key, off2);
                key = (o < key) ? o : key;
            }
            if (l15 == 0)
                atomicMin(&best[rowbase + mt * 16 + l4 * 4 + v], key);
        }
    }
}

// ---------------- kernel 3: gather + straight-through output + loss ---
__global__ __launch_bounds__(256) void vq_out_kernel(
    const float* __restrict__ z, const float* __restrict__ emb,
    const unsigned long long* __restrict__ best,
    float* __restrict__ out, float* __restrict__ lsum) {
    const int base = (blockIdx.x * 256 + threadIdx.x) * 8;
    const int row  = base >> 6;
    const int m    = (int)(best[row] & 0xFFFFFFFFull);

    const float4* zp = reinterpret_cast<const float4*>(z + base);
    const float4* qp = reinterpret_cast<const float4*>(emb + (size_t)m * WORD + (base & 63));
    float4* op = reinterpret_cast<float4*>(out + base);

    float s = 0.f;
#pragma unroll
    for (int i = 0; i < 2; ++i) {
        float4 zv = zp[i];
        float4 qv = qp[i];
        float dx = qv.x - zv.x, dy = qv.y - zv.y, dz = qv.z - zv.z, dw = qv.w - zv.w;
        float4 ov;
        ov.x = zv.x + dx; ov.y = zv.y + dy; ov.z = zv.z + dz; ov.w = zv.w + dw;
        op[i] = ov;
        s += dx*dx + dy*dy + dz*dz + dw*dw;
    }

#pragma unroll
    for (int off = 32; off > 0; off >>= 1) s += __shfl_down(s, off);
    __shared__ float wsum[4];
    int lane = threadIdx.x & 63, wid = threadIdx.x >> 6;
    if (lane == 0) wsum[wid] = s;
    __syncthreads();
    if (threadIdx.x == 0)
        atomicAdd(lsum, (wsum[0] + wsum[1]) + (wsum[2] + wsum[3]));
}

// ---------------- kernel 4: finalize loss -----------------------------
__global__ void vq_loss_kernel(const float* __restrict__ lsum,
                               float* __restrict__ loss_out) {
    float mean = lsum[0] * (1.0f / (float)NELEM);
    loss_out[0] = mean + 2.5f * mean;
}

extern "C" void kernel_launch(void* const* d_in, const int* in_sizes, int n_in,
                              void* d_out, int out_size, void* d_ws, size_t ws_size,
                              hipStream_t stream) {
    const float* z   = (const float*)d_in[0];   // z_mean (2048,1024)
    // d_in[1] = z_log_var, unused by the reference
    const float* emb = (const float*)d_in[2];   // (8192,64)
    float* out = (float*)d_out;                 // [z_q_st flat (2097152), loss]

    // ws layout: epack 3 MB | e2 32 KB | best 256 KB | lsum 4 B
    bf16x8* epack = (bf16x8*)d_ws;
    float*  e2    = (float*)((char*)d_ws + (size_t)PKTS * 16);
    unsigned long long* best =
        (unsigned long long*)((char*)e2 + NB_WORD * sizeof(float));
    float* lsum = (float*)((char*)best + NROWS * sizeof(unsigned long long));

    hipMemsetAsync(best, 0xFF, NROWS * sizeof(unsigned long long), stream);
    hipMemsetAsync(lsum, 0, sizeof(float), stream);

    vq_prep_kernel<<<NB_WORD / 256, 256, 0, stream>>>(emb, e2, epack);
    vq_argmin_kernel<<<dim3(NROWS / 128, NCHUNK), 256, 0, stream>>>(
        z, epack, e2, best);
    vq_out_kernel<<<NELEM / (256 * 8), 256, 0, stream>>>(z, emb, best, out, lsum);
    vq_loss_kernel<<<1, 1, 0, stream>>>(lsum, out + NELEM);
}